// Round 16
// baseline (146.578 us; speedup 1.0000x reference)
//
#include <hip/hip_runtime.h>
#include <hip/hip_bf16.h>

#define B_   4
#define C_   256
#define HW_  4096
#define GR_  32
#define CPG_ 8
#define EPS_ 1e-5f
// Q pre-scale: (1/sqrt(C)) * log2(e) so exp(S) == v_exp_f32(S') with no extra mul
#define QSCALE_ 0.09016844005555897f
#define RSQRT2_ 0.70710678118654752f

typedef short bf16x8 __attribute__((ext_vector_type(8)));
typedef short bf16x4 __attribute__((ext_vector_type(4)));
typedef float f32x4  __attribute__((ext_vector_type(4)));
typedef unsigned short u16x4 __attribute__((ext_vector_type(4)));
typedef unsigned int u32x4 __attribute__((ext_vector_type(4)));

__device__ __forceinline__ unsigned short f2bf(float f) {
  unsigned int x; __builtin_memcpy(&x, &f, 4);
  x = x + 0x7FFFu + ((x >> 16) & 1u);
  return (unsigned short)(x >> 16);
}
__device__ __forceinline__ unsigned int cvtpk(float lo, float hi) {
  unsigned int r;
  asm("v_cvt_pk_bf16_f32 %0, %1, %2" : "=v"(r) : "v"(lo), "v"(hi));
  return r;
}
__device__ __forceinline__ float exp2v(float x) {
  float r;
  asm("v_exp_f32 %0, %1" : "=v"(r) : "v"(x));
  return r;
}

#define GP(p) ((const __attribute__((address_space(1))) void*)(p))
#define LP(p) ((__attribute__((address_space(3))) void*)(p))

// ---------------- K_w: weights fp32 -> bf16 (q-rows pre-scaled by log2e/16) ----------
__global__ __launch_bounds__(256) void wcvt(const float* __restrict__ wqkv,
                                            const float* __restrict__ bqkv,
                                            const float* __restrict__ wout,
                                            unsigned short* __restrict__ wbf,
                                            float* __restrict__ bias_s) {
  int i = blockIdx.x * 256 + threadIdx.x;
  const int NQ = 768 * 256, NO = 256 * 256;
  if (i < NQ) {
    int o = i >> 8;
    float s = ((o % 192) < 64) ? QSCALE_ : 1.0f;
    wbf[i] = f2bf(wqkv[i] * s);
  } else if (i < NQ + NO) {
    wbf[i] = f2bf(wout[i - NQ]);
  } else if (i < NQ + NO + 768) {
    int o = i - NQ - NO;
    float s = ((o % 192) < 64) ? QSCALE_ : 1.0f;
    bias_s[o] = bqkv[o] * s;
  }
}

// ---------------- K0: group-norm stats (mean, rstd) per (b, group) ----------------
__global__ __launch_bounds__(256) void gn_stats(const float* __restrict__ x,
                                                float* __restrict__ stats) {
  int bg = blockIdx.x;  // b*32 + g ; group = 8 consecutive channels
  const float4* p = (const float4*)(x + (size_t)bg * (CPG_ * HW_));
  float s = 0.f, ss = 0.f;
  for (int i = threadIdx.x; i < (CPG_ * HW_ / 4); i += 256) {
    float4 v = p[i];
    s  += v.x + v.y + v.z + v.w;
    ss += v.x * v.x + v.y * v.y + v.z * v.z + v.w * v.w;
  }
  #pragma unroll
  for (int off = 32; off > 0; off >>= 1) {
    s  += __shfl_down(s, off, 64);
    ss += __shfl_down(ss, off, 64);
  }
  __shared__ float rs[4], rss[4];
  int wv = threadIdx.x >> 6;
  if ((threadIdx.x & 63) == 0) { rs[wv] = s; rss[wv] = ss; }
  __syncthreads();
  if (threadIdx.x == 0) {
    float S = rs[0] + rs[1] + rs[2] + rs[3];
    float SS = rss[0] + rss[1] + rss[2] + rss[3];
    float mean = S * (1.f / (CPG_ * HW_));
    float var = SS * (1.f / (CPG_ * HW_)) - mean * mean;
    stats[bg * 2 + 0] = mean;
    stats[bg * 2 + 1] = rsqrtf(var + EPS_);
  }
}

// ---------------- K1: normalize -> bf16, LDS-transposed to xnt[b][p][c] -------------
__global__ __launch_bounds__(256) void gn_apply_t(const float* __restrict__ x,
                                                  const float* __restrict__ stats,
                                                  const float* __restrict__ gamma,
                                                  const float* __restrict__ beta,
                                                  unsigned short* __restrict__ xnt) {
  int p0 = blockIdx.x * 64;
  int c0 = blockIdx.y * 64;
  int b  = blockIdx.z;
  int t = threadIdx.x;
  int cl16 = t & 15;
  int row16 = t >> 4;    // 0..15
  __shared__ unsigned short tile[64][66];  // [c][p], pitch 66 breaks bank alignment
  #pragma unroll
  for (int i = 0; i < 4; ++i) {
    int c = c0 + i * 16 + row16;
    int bg = b * GR_ + (c >> 3);
    float mean = stats[bg * 2], rstd = stats[bg * 2 + 1];
    float a = rstd * gamma[c];
    float bb = beta[c] - mean * a;
    float4 v = *(const float4*)&x[((size_t)(b * C_ + c)) * HW_ + p0 + cl16 * 4];
    u16x4 o;
    o[0] = f2bf(v.x * a + bb); o[1] = f2bf(v.y * a + bb);
    o[2] = f2bf(v.z * a + bb); o[3] = f2bf(v.w * a + bb);
    *(u16x4*)&tile[i * 16 + row16][cl16 * 4] = o;
  }
  __syncthreads();
  #pragma unroll
  for (int i = 0; i < 4; ++i) {
    int pp = i * 16 + row16;
    u16x4 o;
    #pragma unroll
    for (int k = 0; k < 4; ++k) o[k] = tile[cl16 * 4 + k][pp];
    *(u16x4*)&xnt[((size_t)b * HW_ + p0 + pp) * C_ + c0 + cl16 * 4] = o;
  }
}

// ---------------- K2: QKV GEMM, fused over all 768 rows, LDS-staged B ---------------
// One block per (p-tile, b). B-slice xnt[p0..p0+63][0..255] (32KB) staged ONCE via
// global_load_lds (linear LDS dest, inverse-swizzled global source, granule ^ (row&7));
// all 12 y-blocks (48 row-tiles; wave w -> rt = w*6+j) computed from it. B-frag reads
// reuse each LDS read across 6 row-tiles. MFMA math bit-identical to prior rounds.
__global__ __launch_bounds__(512) void gemm_qkv(const unsigned short* __restrict__ wbf,
                                                const float* __restrict__ bias_s,
                                                const unsigned short* __restrict__ xnt,
                                                unsigned short* __restrict__ qt,
                                                unsigned short* __restrict__ ktb,
                                                unsigned short* __restrict__ vb) {
  int p0 = blockIdx.x * 64;
  int b  = blockIdx.y;
  int lane = threadIdx.x & 63, wv = threadIdx.x >> 6;   // wv 0..7
  int cl = lane & 15, g = lane >> 4;

  __shared__ unsigned short bt[64 * 256];   // [p][c], granule-swizzled, 32KB

  // ---- stage: each wave 4 instrs x 1KB (2 rows each); rows wv*8 .. wv*8+7
  {
    const unsigned short* xb = xnt + ((size_t)b * HW_ + p0) * C_;
    int rowl = lane >> 5;       // 0/1: row within instr
    int grl  = lane & 31;       // linear granule (16B) within row
    #pragma unroll
    for (int i = 0; i < 4; ++i) {
      int row = wv * 8 + i * 2 + rowl;
      int sgr = grl ^ (row & 7);           // inverse swizzle on SOURCE
      __builtin_amdgcn_global_load_lds(GP(xb + (size_t)row * C_ + sgr * 8),
                                       LP(bt + (wv * 8 + i * 2) * C_), 16, 0, 0);
    }
  }
  __syncthreads();

  f32x4 z = {0.f, 0.f, 0.f, 0.f};
  f32x4 acc[6][4];
  #pragma unroll
  for (int j = 0; j < 6; ++j)
    #pragma unroll
    for (int nt = 0; nt < 4; ++nt) acc[j][nt] = z;

  const char* btc = (const char*)bt;
  for (int kc = 0; kc < C_; kc += 32) {
    bf16x8 bfr[4];
    #pragma unroll
    for (int nt = 0; nt < 4; ++nt) {
      int row = nt * 16 + cl;
      bfr[nt] = *(const bf16x8*)(btc + row * 512 + ((((kc >> 3) + g) ^ (cl & 7)) << 4));
    }
    #pragma unroll
    for (int j = 0; j < 6; ++j) {
      int rt = wv * 6 + j;
      bf16x8 af = *(const bf16x8*)&wbf[(size_t)(rt * 16 + cl) * C_ + kc + g * 8];
      #pragma unroll
      for (int nt = 0; nt < 4; ++nt)
        acc[j][nt] = __builtin_amdgcn_mfma_f32_16x16x32_bf16(af, bfr[nt], acc[j][nt], 0, 0, 0);
    }
  }

  // ---- epilogue: rt -> y = rt>>2 (h = y/3, type = y%3), olocal = (rt&3)*16+g*4
  #pragma unroll
  for (int j = 0; j < 6; ++j) {
    int rt = wv * 6 + j;
    int y = rt >> 2;
    int h = y / 3, type = y - h * 3;
    int bh = b * 4 + h;
    int olocal = (rt & 3) * 16 + g * 4;
    int obase = rt * 16 + g * 4;
    if (type == 2) {  // V: [d][key]
      unsigned short* dst = vb + (size_t)bh * 64 * HW_;
      #pragma unroll
      for (int r = 0; r < 4; ++r) {
        float bv = bias_s[obase + r];
        #pragma unroll
        for (int nt = 0; nt < 4; ++nt)
          dst[(size_t)(olocal + r) * HW_ + p0 + nt * 16 + cl] = f2bf(acc[j][nt][r] + bv);
      }
    } else {          // Q or K: [key][d], vectorized u16x4
      unsigned short* dst = (type == 0 ? qt : ktb) + (size_t)bh * HW_ * 64;
      #pragma unroll
      for (int nt = 0; nt < 4; ++nt) {
        int p = p0 + nt * 16 + cl;
        u16x4 o4;
        #pragma unroll
        for (int r = 0; r < 4; ++r) o4[r] = f2bf(acc[j][nt][r] + bias_s[obase + r]);
        *(u16x4*)&dst[(size_t)p * 64 + olocal] = o4;
      }
    }
  }
}

// ---------------- K3: flash attention, 8 waves x 32 QUERIES/WAVE (R14, unchanged) ---
__global__ __launch_bounds__(512) void flash_attn(const unsigned short* __restrict__ qt,
                                                  const unsigned short* __restrict__ ktb,
                                                  const unsigned short* __restrict__ vb,
                                                  unsigned short* __restrict__ attnt) {
  int qtile = blockIdx.x;   // 16 tiles of 256 queries
  int bh = blockIdx.y;      // 16
  int lane = threadIdx.x & 63, wv = threadIdx.x >> 6;   // wv 0..7
  int cl = lane & 15, g = lane >> 4;
  int r8 = lane >> 3;                 // 0..7: row-within-8 for staging
  int gi = (lane & 7) ^ r8;           // inverse-swizzled 16B-granule for staging

  const unsigned short* qtb = qt  + (size_t)bh * HW_ * 64;
  const unsigned short* ktp = ktb + (size_t)bh * HW_ * 64;
  const unsigned short* vbp = vb  + (size_t)bh * 64 * HW_;

  __shared__ unsigned short smem[2][8192];

  int qpix0 = qtile * 256 + wv * 32 + cl;        // half 0 query
  bf16x8 qf0[2], qf1[2];
  qf0[0] = *(const bf16x8*)&qtb[(size_t)qpix0 * 64 + g * 8];
  qf0[1] = *(const bf16x8*)&qtb[(size_t)qpix0 * 64 + 32 + g * 8];
  qf1[0] = *(const bf16x8*)&qtb[(size_t)(qpix0 + 16) * 64 + g * 8];
  qf1[1] = *(const bf16x8*)&qtb[(size_t)(qpix0 + 16) * 64 + 32 + g * 8];

  f32x4 z = {0.f, 0.f, 0.f, 0.f};
  f32x4 oacc0[4] = {z, z, z, z};
  f32x4 oacc1[4] = {z, z, z, z};
  f32x4 lfrag0 = z, lfrag1 = z;
  const bf16x4 ones = {(short)0x3F80, (short)0x3F80, (short)0x3F80, (short)0x3F80};

  int rdo = cl * 128 + ((g * 16) ^ ((cl & 7) << 4));
  int vbase = cl * 128 + (g & 1) * 8;
  int vxor  = (cl & 7) << 4;
  int ghalf = g >> 1;

  const unsigned short* kp = ktp + (size_t)(wv * 8 + r8) * 64 + gi * 8;
  const unsigned short* vp = vbp + (size_t)(wv * 8 + r8) * HW_ + gi * 8;

#define STAGE(bi) do {                                                              \
    unsigned short* sb = &smem[bi][0];                                              \
    __builtin_amdgcn_global_load_lds(GP(kp), LP(sb + wv * 512),        16, 0, 0);   \
    __builtin_amdgcn_global_load_lds(GP(vp), LP(sb + 4096 + wv * 512), 16, 0, 0);   \
    kp += 64 * 64;                                                                  \
    vp += 64;                                                                       \
  } while (0)

  STAGE(0);
  __syncthreads();

  int cur = 0;
  for (int t = 0; t < 64; ++t) {
    if (t < 63) STAGE(cur ^ 1);

    const char* kb  = (const char*)&smem[cur][0];
    const char* vbx = (const char*)&smem[cur][4096];

    f32x4 sacc0[4] = {z, z, z, z};
    f32x4 sacc1[4] = {z, z, z, z};
    __builtin_amdgcn_s_setprio(1);
    #pragma unroll
    for (int nt = 0; nt < 4; ++nt) {
      #pragma unroll
      for (int ks = 0; ks < 2; ++ks) {
        bf16x8 kf = *(const bf16x8*)(kb + rdo + nt * 2048 + ks * 64);
        sacc0[nt] = __builtin_amdgcn_mfma_f32_16x16x32_bf16(kf, qf0[ks], sacc0[nt], 0, 0, 0);
        sacc1[nt] = __builtin_amdgcn_mfma_f32_16x16x32_bf16(kf, qf1[ks], sacc1[nt], 0, 0, 0);
      }
    }
    __builtin_amdgcn_s_setprio(0);

    unsigned int pk01a[4], pk23a[4], pk01b[4], pk23b[4];
    #pragma unroll
    for (int nt = 0; nt < 4; ++nt) {
      pk01a[nt] = cvtpk(exp2v(sacc0[nt][0]), exp2v(sacc0[nt][1]));
      pk23a[nt] = cvtpk(exp2v(sacc0[nt][2]), exp2v(sacc0[nt][3]));
      pk01b[nt] = cvtpk(exp2v(sacc1[nt][0]), exp2v(sacc1[nt][1]));
      pk23b[nt] = cvtpk(exp2v(sacc1[nt][2]), exp2v(sacc1[nt][3]));
    }

    __builtin_amdgcn_s_setprio(1);
    #pragma unroll
    for (int nt = 0; nt < 4; ++nt) {
      union { unsigned int u[2]; bf16x4 v; } pb0, pb1;
      pb0.u[0] = pk01a[nt]; pb0.u[1] = pk23a[nt];
      pb1.u[0] = pk01b[nt]; pb1.u[1] = pk23b[nt];
      lfrag0 = __builtin_amdgcn_mfma_f32_16x16x16bf16_1k(ones, pb0.v, lfrag0, 0, 0, 0);
      lfrag1 = __builtin_amdgcn_mfma_f32_16x16x16bf16_1k(ones, pb1.v, lfrag1, 0, 0, 0);
      int gsw = ((nt * 2 + ghalf) << 4) ^ vxor;
      #pragma unroll
      for (int dt = 0; dt < 4; ++dt) {
        bf16x4 vf = *(const bf16x4*)(vbx + dt * 2048 + vbase + gsw);
        oacc0[dt] = __builtin_amdgcn_mfma_f32_16x16x16bf16_1k(vf, pb0.v, oacc0[dt], 0, 0, 0);
        oacc1[dt] = __builtin_amdgcn_mfma_f32_16x16x16bf16_1k(vf, pb1.v, oacc1[dt], 0, 0, 0);
      }
    }
    __builtin_amdgcn_s_setprio(0);
    __syncthreads();
    cur ^= 1;
  }
#undef STAGE

  int b = bh >> 2, h = bh & 3;
  float rl0 = 1.f / lfrag0[0];
  float rl1 = 1.f / lfrag1[0];
  unsigned short* at0 = attnt + ((size_t)b * HW_ + qpix0) * C_ + h * 64;
  unsigned short* at1 = attnt + ((size_t)b * HW_ + qpix0 + 16) * C_ + h * 64;
  #pragma unroll
  for (int dt = 0; dt < 4; ++dt) {
    u16x4 o4a, o4b;
    #pragma unroll
    for (int r = 0; r < 4; ++r) {
      o4a[r] = f2bf(oacc0[dt][r] * rl0);
      o4b[r] = f2bf(oacc1[dt][r] * rl1);
    }
    *(u16x4*)&at0[dt * 16 + g * 4] = o4a;
    *(u16x4*)&at1[dt * 16 + g * 4] = o4b;
  }
}

// ---------------- K4: out projection fused over all 256 rows, LDS-staged B ----------
// Same staging pattern as gemm_qkv (attnt is [p][c], c-contiguous). Wave w handles
// row-tiles rt = w*2 + j (j=0..1). + bias + residual + /sqrt(2).
__global__ __launch_bounds__(512) void gemm_out(const unsigned short* __restrict__ wbf_out,
                                                const float* __restrict__ bias,
                                                const unsigned short* __restrict__ attnt,
                                                const float* __restrict__ x,
                                                float* __restrict__ out) {
  int p0 = blockIdx.x * 64;
  int b  = blockIdx.y;
  int lane = threadIdx.x & 63, wv = threadIdx.x >> 6;
  int cl = lane & 15, g = lane >> 4;

  __shared__ unsigned short bt[64 * 256];   // [p][c], granule-swizzled, 32KB

  {
    const unsigned short* ab = attnt + ((size_t)b * HW_ + p0) * C_;
    int rowl = lane >> 5;
    int grl  = lane & 31;
    #pragma unroll
    for (int i = 0; i < 4; ++i) {
      int row = wv * 8 + i * 2 + rowl;
      int sgr = grl ^ (row & 7);
      __builtin_amdgcn_global_load_lds(GP(ab + (size_t)row * C_ + sgr * 8),
                                       LP(bt + (wv * 8 + i * 2) * C_), 16, 0, 0);
    }
  }
  __syncthreads();

  f32x4 z = {0.f, 0.f, 0.f, 0.f};
  f32x4 acc[2][4];
  #pragma unroll
  for (int j = 0; j < 2; ++j)
    #pragma unroll
    for (int nt = 0; nt < 4; ++nt) acc[j][nt] = z;

  const char* btc = (const char*)bt;
  for (int kc = 0; kc < C_; kc += 32) {
    bf16x8 bfr[4];
    #pragma unroll
    for (int nt = 0; nt < 4; ++nt) {
      int row = nt * 16 + cl;
      bfr[nt] = *(const bf16x8*)(btc + row * 512 + ((((kc >> 3) + g) ^ (cl & 7)) << 4));
    }
    #pragma unroll
    for (int j = 0; j < 2; ++j) {
      int rt = wv * 2 + j;
      bf16x8 af = *(const bf16x8*)&wbf_out[(size_t)(rt * 16 + cl) * C_ + kc + g * 8];
      #pragma unroll
      for (int nt = 0; nt < 4; ++nt)
        acc[j][nt] = __builtin_amdgcn_mfma_f32_16x16x32_bf16(af, bfr[nt], acc[j][nt], 0, 0, 0);
    }
  }

  const float* xb = x + (size_t)b * C_ * HW_;
  float* ob = out + (size_t)b * C_ * HW_;
  #pragma unroll
  for (int j = 0; j < 2; ++j) {
    int rt = wv * 2 + j;
    #pragma unroll
    for (int r = 0; r < 4; ++r) {
      int o = rt * 16 + g * 4 + r;
      float bv = bias[o];
      #pragma unroll
      for (int nt = 0; nt < 4; ++nt) {
        int p = p0 + nt * 16 + cl;
        size_t idx = (size_t)o * HW_ + p;
        ob[idx] = (acc[j][nt][r] + bv + xb[idx]) * RSQRT2_;
      }
    }
  }
}

extern "C" void kernel_launch(void* const* d_in, const int* in_sizes, int n_in,
                              void* d_out, int out_size, void* d_ws, size_t ws_size,
                              hipStream_t stream) {
  const float* x     = (const float*)d_in[0];
  const float* gamma = (const float*)d_in[1];
  const float* beta  = (const float*)d_in[2];
  const float* w_qkv = (const float*)d_in[3];
  const float* b_qkv = (const float*)d_in[4];
  const float* w_out = (const float*)d_in[5];
  const float* b_out = (const float*)d_in[6];
  float* out = (float*)d_out;

  // Workspace layout: wbf = (768+256)*256*2 = 524,288 B. attnt ALIASES xnt
  // (xnt dead after gemm_qkv's staging reads; flash_attn runs after). 34 MB total.
  char* ws = (char*)d_ws;
  float* stats           = (float*)ws;                              // 1 KB
  float* bias_s          = (float*)(ws + 1024);                     // 3 KB
  unsigned short* wbf    = (unsigned short*)(ws + 4096);            // 524,288 B
  unsigned short* xnt    = (unsigned short*)(ws + 528384);          // 8.39 MB
  unsigned short* qt     = (unsigned short*)(ws + 8916992);         // 8.39 MB
  unsigned short* ktb    = (unsigned short*)(ws + 17305600);        // 8.39 MB
  unsigned short* vb     = (unsigned short*)(ws + 25694208);        // 8.39 MB -> 34,082,816
  unsigned short* attnt  = xnt;                                     // alias (xnt dead after gemm_qkv)

  wcvt<<<dim3(1028), dim3(256), 0, stream>>>(w_qkv, b_qkv, w_out, wbf, bias_s);
  gn_stats<<<dim3(128), dim3(256), 0, stream>>>(x, stats);
  gn_apply_t<<<dim3(64, 4, 4), dim3(256), 0, stream>>>(x, stats, gamma, beta, xnt);
  gemm_qkv<<<dim3(64, 4), dim3(512), 0, stream>>>(wbf, bias_s, xnt, qt, ktb, vb);
  flash_attn<<<dim3(16, 16), dim3(512), 0, stream>>>(qt, ktb, vb, attnt);
  gemm_out<<<dim3(64, 4), dim3(512), 0, stream>>>(wbf + 768 * 256, b_out, attnt, x, out);
}

// Round 17
// 143.444 us; speedup vs baseline: 1.0219x; 1.0219x over previous
//
#include <hip/hip_runtime.h>
#include <hip/hip_bf16.h>

#define B_   4
#define C_   256
#define HW_  4096
#define GR_  32
#define CPG_ 8
#define EPS_ 1e-5f
// Q pre-scale: (1/sqrt(C)) * log2(e) so exp(S) == v_exp_f32(S') with no extra mul
#define QSCALE_ 0.09016844005555897f
#define RSQRT2_ 0.70710678118654752f

typedef short bf16x8 __attribute__((ext_vector_type(8)));
typedef short bf16x4 __attribute__((ext_vector_type(4)));
typedef float f32x4  __attribute__((ext_vector_type(4)));
typedef unsigned short u16x4 __attribute__((ext_vector_type(4)));
typedef unsigned int u32x4 __attribute__((ext_vector_type(4)));

__device__ __forceinline__ unsigned short f2bf(float f) {
  unsigned int x; __builtin_memcpy(&x, &f, 4);
  x = x + 0x7FFFu + ((x >> 16) & 1u);
  return (unsigned short)(x >> 16);
}
__device__ __forceinline__ unsigned int cvtpk(float lo, float hi) {
  unsigned int r;
  asm("v_cvt_pk_bf16_f32 %0, %1, %2" : "=v"(r) : "v"(lo), "v"(hi));
  return r;
}
__device__ __forceinline__ float exp2v(float x) {
  float r;
  asm("v_exp_f32 %0, %1" : "=v"(r) : "v"(x));
  return r;
}

#define GP(p) ((const __attribute__((address_space(1))) void*)(p))
#define LP(p) ((__attribute__((address_space(3))) void*)(p))

// ---------------- K_w: weights fp32 -> bf16 (q-rows pre-scaled by log2e/16) ----------
__global__ __launch_bounds__(256) void wcvt(const float* __restrict__ wqkv,
                                            const float* __restrict__ bqkv,
                                            const float* __restrict__ wout,
                                            unsigned short* __restrict__ wbf,
                                            float* __restrict__ bias_s) {
  int i = blockIdx.x * 256 + threadIdx.x;
  const int NQ = 768 * 256, NO = 256 * 256;
  if (i < NQ) {
    int o = i >> 8;
    float s = ((o % 192) < 64) ? QSCALE_ : 1.0f;
    wbf[i] = f2bf(wqkv[i] * s);
  } else if (i < NQ + NO) {
    wbf[i] = f2bf(wout[i - NQ]);
  } else if (i < NQ + NO + 768) {
    int o = i - NQ - NO;
    float s = ((o % 192) < 64) ? QSCALE_ : 1.0f;
    bias_s[o] = bqkv[o] * s;
  }
}

// ---------------- K0: group-norm stats (mean, rstd) per (b, group) ----------------
__global__ __launch_bounds__(256) void gn_stats(const float* __restrict__ x,
                                                float* __restrict__ stats) {
  int bg = blockIdx.x;  // b*32 + g ; group = 8 consecutive channels
  const float4* p = (const float4*)(x + (size_t)bg * (CPG_ * HW_));
  float s = 0.f, ss = 0.f;
  for (int i = threadIdx.x; i < (CPG_ * HW_ / 4); i += 256) {
    float4 v = p[i];
    s  += v.x + v.y + v.z + v.w;
    ss += v.x * v.x + v.y * v.y + v.z * v.z + v.w * v.w;
  }
  #pragma unroll
  for (int off = 32; off > 0; off >>= 1) {
    s  += __shfl_down(s, off, 64);
    ss += __shfl_down(ss, off, 64);
  }
  __shared__ float rs[4], rss[4];
  int wv = threadIdx.x >> 6;
  if ((threadIdx.x & 63) == 0) { rs[wv] = s; rss[wv] = ss; }
  __syncthreads();
  if (threadIdx.x == 0) {
    float S = rs[0] + rs[1] + rs[2] + rs[3];
    float SS = rss[0] + rss[1] + rss[2] + rss[3];
    float mean = S * (1.f / (CPG_ * HW_));
    float var = SS * (1.f / (CPG_ * HW_)) - mean * mean;
    stats[bg * 2 + 0] = mean;
    stats[bg * 2 + 1] = rsqrtf(var + EPS_);
  }
}

// ---------------- K2: QKV GEMM with FUSED GroupNorm-apply (xnt eliminated) ----------
// One block per (p-tile, b). Phase 0: load x[c][p0..p0+63] f32 (coalesced 256B rows),
// normalize, LDS-scratch transpose (gn_apply_t's verified pattern), write bf16 into
// swizzled bt[p][c] (granule (c/8)^(p&7) == GEMM read swizzle ((kc>>3)+g)^(cl&7)).
// Phase 1: GEMM over all 768 rows, bit-identical math to R16.
__global__ __launch_bounds__(512) void gemm_qkv(const unsigned short* __restrict__ wbf,
                                                const float* __restrict__ bias_s,
                                                const float* __restrict__ x,
                                                const float* __restrict__ stats,
                                                const float* __restrict__ gamma,
                                                const float* __restrict__ beta,
                                                unsigned short* __restrict__ qt,
                                                unsigned short* __restrict__ ktb,
                                                unsigned short* __restrict__ vb) {
  int p0 = blockIdx.x * 64;
  int b  = blockIdx.y;
  int lane = threadIdx.x & 63, wv = threadIdx.x >> 6;   // wv 0..7
  int cl = lane & 15, g = lane >> 4;

  __shared__ unsigned short bt[64 * 256];     // [p][c], granule-swizzled, 32KB
  __shared__ unsigned short scratch[64][68];  // [c_local][p], pitch 68

  // ---- Phase 0: normalize + transpose, 4 chunks of 64 channels
  {
    int t = threadIdx.x;
    int cl16 = t & 15;       // p-quad index
    int row32 = t >> 4;      // 0..31
    const float* xb = x + (size_t)b * C_ * HW_;
    #pragma unroll
    for (int cc = 0; cc < 4; ++cc) {
      int c0 = cc * 64;
      #pragma unroll
      for (int i = 0; i < 2; ++i) {
        int cloc = i * 32 + row32;
        int c = c0 + cloc;
        int bg = b * GR_ + (c >> 3);
        float mean = stats[bg * 2], rstd = stats[bg * 2 + 1];
        float a = rstd * gamma[c];
        float bb = beta[c] - mean * a;
        float4 v = *(const float4*)&xb[(size_t)c * HW_ + p0 + cl16 * 4];
        u16x4 o;
        o[0] = f2bf(v.x * a + bb); o[1] = f2bf(v.y * a + bb);
        o[2] = f2bf(v.z * a + bb); o[3] = f2bf(v.w * a + bb);
        *(u16x4*)&scratch[cloc][cl16 * 4] = o;
      }
      __syncthreads();
      #pragma unroll
      for (int i = 0; i < 2; ++i) {
        int pp = i * 32 + row32;
        u16x4 o;
        #pragma unroll
        for (int k = 0; k < 4; ++k) o[k] = scratch[cl16 * 4 + k][pp];
        int cbyte = (c0 + cl16 * 4) * 2;               // 0..511
        int sw = (((cbyte >> 4) ^ (pp & 7)) << 4) | (cbyte & 15);
        *(u16x4*)((char*)bt + pp * 512 + sw) = o;
      }
      __syncthreads();
    }
  }

  // ---- Phase 1: GEMM (identical to verified R16 path)
  f32x4 z = {0.f, 0.f, 0.f, 0.f};
  f32x4 acc[6][4];
  #pragma unroll
  for (int j = 0; j < 6; ++j)
    #pragma unroll
    for (int nt = 0; nt < 4; ++nt) acc[j][nt] = z;

  const char* btc = (const char*)bt;
  for (int kc = 0; kc < C_; kc += 32) {
    bf16x8 bfr[4];
    #pragma unroll
    for (int nt = 0; nt < 4; ++nt) {
      int row = nt * 16 + cl;
      bfr[nt] = *(const bf16x8*)(btc + row * 512 + ((((kc >> 3) + g) ^ (cl & 7)) << 4));
    }
    #pragma unroll
    for (int j = 0; j < 6; ++j) {
      int rt = wv * 6 + j;
      bf16x8 af = *(const bf16x8*)&wbf[(size_t)(rt * 16 + cl) * C_ + kc + g * 8];
      #pragma unroll
      for (int nt = 0; nt < 4; ++nt)
        acc[j][nt] = __builtin_amdgcn_mfma_f32_16x16x32_bf16(af, bfr[nt], acc[j][nt], 0, 0, 0);
    }
  }

  // ---- epilogue: rt -> y = rt>>2 (h = y/3, type = y%3), olocal = (rt&3)*16+g*4
  #pragma unroll
  for (int j = 0; j < 6; ++j) {
    int rt = wv * 6 + j;
    int y = rt >> 2;
    int h = y / 3, type = y - h * 3;
    int bh = b * 4 + h;
    int olocal = (rt & 3) * 16 + g * 4;
    int obase = rt * 16 + g * 4;
    if (type == 2) {  // V: [d][key]
      unsigned short* dst = vb + (size_t)bh * 64 * HW_;
      #pragma unroll
      for (int r = 0; r < 4; ++r) {
        float bv = bias_s[obase + r];
        #pragma unroll
        for (int nt = 0; nt < 4; ++nt)
          dst[(size_t)(olocal + r) * HW_ + p0 + nt * 16 + cl] = f2bf(acc[j][nt][r] + bv);
      }
    } else {          // Q or K: [key][d], vectorized u16x4
      unsigned short* dst = (type == 0 ? qt : ktb) + (size_t)bh * HW_ * 64;
      #pragma unroll
      for (int nt = 0; nt < 4; ++nt) {
        int p = p0 + nt * 16 + cl;
        u16x4 o4;
        #pragma unroll
        for (int r = 0; r < 4; ++r) o4[r] = f2bf(acc[j][nt][r] + bias_s[obase + r]);
        *(u16x4*)&dst[(size_t)p * 64 + olocal] = o4;
      }
    }
  }
}

// ---------------- K3: flash attention, 8 waves x 32 q/wave; l on VALU (R9-style) ----
// l-MFMAs removed from the loaded matrix pipe (MfmaUtil 49 > VALU 34): lacc += p
// per-lane f32 (keys {nt*16+g*4+r} in-lane), reduced once via 2 shfl in epilogue.
__global__ __launch_bounds__(512) void flash_attn(const unsigned short* __restrict__ qt,
                                                  const unsigned short* __restrict__ ktb,
                                                  const unsigned short* __restrict__ vb,
                                                  unsigned short* __restrict__ attnt) {
  int qtile = blockIdx.x;   // 16 tiles of 256 queries
  int bh = blockIdx.y;      // 16
  int lane = threadIdx.x & 63, wv = threadIdx.x >> 6;   // wv 0..7
  int cl = lane & 15, g = lane >> 4;
  int r8 = lane >> 3;                 // 0..7: row-within-8 for staging
  int gi = (lane & 7) ^ r8;           // inverse-swizzled 16B-granule for staging

  const unsigned short* qtb = qt  + (size_t)bh * HW_ * 64;
  const unsigned short* ktp = ktb + (size_t)bh * HW_ * 64;
  const unsigned short* vbp = vb  + (size_t)bh * 64 * HW_;

  __shared__ unsigned short smem[2][8192];

  int qpix0 = qtile * 256 + wv * 32 + cl;        // half 0 query
  bf16x8 qf0[2], qf1[2];
  qf0[0] = *(const bf16x8*)&qtb[(size_t)qpix0 * 64 + g * 8];
  qf0[1] = *(const bf16x8*)&qtb[(size_t)qpix0 * 64 + 32 + g * 8];
  qf1[0] = *(const bf16x8*)&qtb[(size_t)(qpix0 + 16) * 64 + g * 8];
  qf1[1] = *(const bf16x8*)&qtb[(size_t)(qpix0 + 16) * 64 + 32 + g * 8];

  f32x4 z = {0.f, 0.f, 0.f, 0.f};
  f32x4 oacc0[4] = {z, z, z, z};
  f32x4 oacc1[4] = {z, z, z, z};
  f32x4 lacc0 = z, lacc1 = z;

  int rdo = cl * 128 + ((g * 16) ^ ((cl & 7) << 4));
  int vbase = cl * 128 + (g & 1) * 8;
  int vxor  = (cl & 7) << 4;
  int ghalf = g >> 1;

  const unsigned short* kp = ktp + (size_t)(wv * 8 + r8) * 64 + gi * 8;
  const unsigned short* vp = vbp + (size_t)(wv * 8 + r8) * HW_ + gi * 8;

#define STAGE(bi) do {                                                              \
    unsigned short* sb = &smem[bi][0];                                              \
    __builtin_amdgcn_global_load_lds(GP(kp), LP(sb + wv * 512),        16, 0, 0);   \
    __builtin_amdgcn_global_load_lds(GP(vp), LP(sb + 4096 + wv * 512), 16, 0, 0);   \
    kp += 64 * 64;                                                                  \
    vp += 64;                                                                       \
  } while (0)

  STAGE(0);
  __syncthreads();

  int cur = 0;
  for (int t = 0; t < 64; ++t) {
    if (t < 63) STAGE(cur ^ 1);

    const char* kb  = (const char*)&smem[cur][0];
    const char* vbx = (const char*)&smem[cur][4096];

    f32x4 sacc0[4] = {z, z, z, z};
    f32x4 sacc1[4] = {z, z, z, z};
    __builtin_amdgcn_s_setprio(1);
    #pragma unroll
    for (int nt = 0; nt < 4; ++nt) {
      #pragma unroll
      for (int ks = 0; ks < 2; ++ks) {
        bf16x8 kf = *(const bf16x8*)(kb + rdo + nt * 2048 + ks * 64);
        sacc0[nt] = __builtin_amdgcn_mfma_f32_16x16x32_bf16(kf, qf0[ks], sacc0[nt], 0, 0, 0);
        sacc1[nt] = __builtin_amdgcn_mfma_f32_16x16x32_bf16(kf, qf1[ks], sacc1[nt], 0, 0, 0);
      }
    }
    __builtin_amdgcn_s_setprio(0);

    // ---- P = exp2(S'); lacc accumulates f32 (VALU pipe); packed pairs ARE PV B-frag
    unsigned int pk01a[4], pk23a[4], pk01b[4], pk23b[4];
    #pragma unroll
    for (int nt = 0; nt < 4; ++nt) {
      f32x4 pa, pbv;
      pa[0] = exp2v(sacc0[nt][0]); pa[1] = exp2v(sacc0[nt][1]);
      pa[2] = exp2v(sacc0[nt][2]); pa[3] = exp2v(sacc0[nt][3]);
      pbv[0] = exp2v(sacc1[nt][0]); pbv[1] = exp2v(sacc1[nt][1]);
      pbv[2] = exp2v(sacc1[nt][2]); pbv[3] = exp2v(sacc1[nt][3]);
      lacc0 += pa;
      lacc1 += pbv;
      pk01a[nt] = cvtpk(pa[0], pa[1]);
      pk23a[nt] = cvtpk(pa[2], pa[3]);
      pk01b[nt] = cvtpk(pbv[0], pbv[1]);
      pk23b[nt] = cvtpk(pbv[2], pbv[3]);
    }

    __builtin_amdgcn_s_setprio(1);
    #pragma unroll
    for (int nt = 0; nt < 4; ++nt) {
      union { unsigned int u[2]; bf16x4 v; } pb0, pb1;
      pb0.u[0] = pk01a[nt]; pb0.u[1] = pk23a[nt];
      pb1.u[0] = pk01b[nt]; pb1.u[1] = pk23b[nt];
      int gsw = ((nt * 2 + ghalf) << 4) ^ vxor;
      #pragma unroll
      for (int dt = 0; dt < 4; ++dt) {
        bf16x4 vf = *(const bf16x4*)(vbx + dt * 2048 + vbase + gsw);
        oacc0[dt] = __builtin_amdgcn_mfma_f32_16x16x16bf16_1k(vf, pb0.v, oacc0[dt], 0, 0, 0);
        oacc1[dt] = __builtin_amdgcn_mfma_f32_16x16x16bf16_1k(vf, pb1.v, oacc1[dt], 0, 0, 0);
      }
    }
    __builtin_amdgcn_s_setprio(0);
    __syncthreads();
    cur ^= 1;
  }
#undef STAGE

  // ---- epilogue: reduce l across the 4 lane-groups (keys {nt*16+g*4+r} in-lane)
  float l0 = lacc0[0] + lacc0[1] + lacc0[2] + lacc0[3];
  l0 += __shfl_xor(l0, 16, 64);
  l0 += __shfl_xor(l0, 32, 64);
  float l1 = lacc1[0] + lacc1[1] + lacc1[2] + lacc1[3];
  l1 += __shfl_xor(l1, 16, 64);
  l1 += __shfl_xor(l1, 32, 64);

  int b = bh >> 2, h = bh & 3;
  float rl0 = 1.f / l0;
  float rl1 = 1.f / l1;
  unsigned short* at0 = attnt + ((size_t)b * HW_ + qpix0) * C_ + h * 64;
  unsigned short* at1 = attnt + ((size_t)b * HW_ + qpix0 + 16) * C_ + h * 64;
  #pragma unroll
  for (int dt = 0; dt < 4; ++dt) {
    u16x4 o4a, o4b;
    #pragma unroll
    for (int r = 0; r < 4; ++r) {
      o4a[r] = f2bf(oacc0[dt][r] * rl0);
      o4b[r] = f2bf(oacc1[dt][r] * rl1);
    }
    *(u16x4*)&at0[dt * 16 + g * 4] = o4a;
    *(u16x4*)&at1[dt * 16 + g * 4] = o4b;
  }
}

// ---------------- K4: out projection fused over all 256 rows, LDS-staged B ----------
__global__ __launch_bounds__(512) void gemm_out(const unsigned short* __restrict__ wbf_out,
                                                const float* __restrict__ bias,
                                                const unsigned short* __restrict__ attnt,
                                                const float* __restrict__ x,
                                                float* __restrict__ out) {
  int p0 = blockIdx.x * 64;
  int b  = blockIdx.y;
  int lane = threadIdx.x & 63, wv = threadIdx.x >> 6;
  int cl = lane & 15, g = lane >> 4;

  __shared__ unsigned short bt[64 * 256];   // [p][c], granule-swizzled, 32KB

  {
    const unsigned short* ab = attnt + ((size_t)b * HW_ + p0) * C_;
    int rowl = lane >> 5;
    int grl  = lane & 31;
    #pragma unroll
    for (int i = 0; i < 4; ++i) {
      int row = wv * 8 + i * 2 + rowl;
      int sgr = grl ^ (row & 7);
      __builtin_amdgcn_global_load_lds(GP(ab + (size_t)row * C_ + sgr * 8),
                                       LP(bt + (wv * 8 + i * 2) * C_), 16, 0, 0);
    }
  }
  __syncthreads();

  f32x4 z = {0.f, 0.f, 0.f, 0.f};
  f32x4 acc[2][4];
  #pragma unroll
  for (int j = 0; j < 2; ++j)
    #pragma unroll
    for (int nt = 0; nt < 4; ++nt) acc[j][nt] = z;

  const char* btc = (const char*)bt;
  for (int kc = 0; kc < C_; kc += 32) {
    bf16x8 bfr[4];
    #pragma unroll
    for (int nt = 0; nt < 4; ++nt) {
      int row = nt * 16 + cl;
      bfr[nt] = *(const bf16x8*)(btc + row * 512 + ((((kc >> 3) + g) ^ (cl & 7)) << 4));
    }
    #pragma unroll
    for (int j = 0; j < 2; ++j) {
      int rt = wv * 2 + j;
      bf16x8 af = *(const bf16x8*)&wbf_out[(size_t)(rt * 16 + cl) * C_ + kc + g * 8];
      #pragma unroll
      for (int nt = 0; nt < 4; ++nt)
        acc[j][nt] = __builtin_amdgcn_mfma_f32_16x16x32_bf16(af, bfr[nt], acc[j][nt], 0, 0, 0);
    }
  }

  const float* xb = x + (size_t)b * C_ * HW_;
  float* ob = out + (size_t)b * C_ * HW_;
  #pragma unroll
  for (int j = 0; j < 2; ++j) {
    int rt = wv * 2 + j;
    #pragma unroll
    for (int r = 0; r < 4; ++r) {
      int o = rt * 16 + g * 4 + r;
      float bv = bias[o];
      #pragma unroll
      for (int nt = 0; nt < 4; ++nt) {
        int p = p0 + nt * 16 + cl;
        size_t idx = (size_t)o * HW_ + p;
        ob[idx] = (acc[j][nt][r] + bv + xb[idx]) * RSQRT2_;
      }
    }
  }
}

extern "C" void kernel_launch(void* const* d_in, const int* in_sizes, int n_in,
                              void* d_out, int out_size, void* d_ws, size_t ws_size,
                              hipStream_t stream) {
  const float* x     = (const float*)d_in[0];
  const float* gamma = (const float*)d_in[1];
  const float* beta  = (const float*)d_in[2];
  const float* w_qkv = (const float*)d_in[3];
  const float* b_qkv = (const float*)d_in[4];
  const float* w_out = (const float*)d_in[5];
  const float* b_out = (const float*)d_in[6];
  float* out = (float*)d_out;

  // Workspace: wbf 524,288 B; attnt standalone (xnt eliminated by the GN fusion).
  // Total ws = 34,082,816 B.
  char* ws = (char*)d_ws;
  float* stats           = (float*)ws;                              // 1 KB
  float* bias_s          = (float*)(ws + 1024);                     // 3 KB
  unsigned short* wbf    = (unsigned short*)(ws + 4096);            // 524,288 B
  unsigned short* attnt  = (unsigned short*)(ws + 528384);          // 8.39 MB
  unsigned short* qt     = (unsigned short*)(ws + 8916992);         // 8.39 MB
  unsigned short* ktb    = (unsigned short*)(ws + 17305600);        // 8.39 MB
  unsigned short* vb     = (unsigned short*)(ws + 25694208);        // 8.39 MB -> 34,082,816

  wcvt<<<dim3(1028), dim3(256), 0, stream>>>(w_qkv, b_qkv, w_out, wbf, bias_s);
  gn_stats<<<dim3(128), dim3(256), 0, stream>>>(x, stats);
  gemm_qkv<<<dim3(64, 4), dim3(512), 0, stream>>>(wbf, bias_s, x, stats, gamma, beta, qt, ktb, vb);
  flash_attn<<<dim3(16, 16), dim3(512), 0, stream>>>(qt, ktb, vb, attnt);
  gemm_out<<<dim3(64, 4), dim3(512), 0, stream>>>(wbf + 768 * 256, b_out, attnt, x, out);
}